// Round 13
// baseline (419.969 us; speedup 1.0000x reference)
//
#include <hip/hip_runtime.h>
#include <hip/hip_bf16.h>
#include <math.h>

typedef __hip_bfloat16 bf16;
typedef __bf16 bhalf;
typedef bhalf bhalf8 __attribute__((ext_vector_type(8)));
typedef float f32x4 __attribute__((ext_vector_type(4)));
typedef unsigned short u16;
typedef u16 u16x4 __attribute__((ext_vector_type(4)));
typedef u16 u16x8 __attribute__((ext_vector_type(8)));

#define D_MODEL   1024
#define D_STATE   64
#define HEADDIM   64
#define D_INNER   2048
#define NHEADS    32
#define CONV_DIM  2176
#define D_IN_PROJ 4256
#define FFN_DIM   4096
#define BSZ       2
#define SEQ       2048
#define NROWS     (BSZ*SEQ)
#define TC        64
#define NCH       (SEQ/TC)

#define AS1 __attribute__((address_space(1)))
#define AS3 __attribute__((address_space(3)))
__device__ __forceinline__ void load_lds16(const void* g, void* l) {
  __builtin_amdgcn_global_load_lds((AS1 void*)g, (AS3 void*)l, 16, 0, 0);
}

__device__ __forceinline__ float bf2f(u16 u) {
  return __uint_as_float(((unsigned)u) << 16);
}
__device__ __forceinline__ u16 f2bbits(float f) {
  bf16 h = __float2bfloat16(f);
  return *(u16*)&h;
}

// ---------------------------------------------------------------------------
// Normalize weight inputs to bf16 copies; vectorized; per-block dtype
// self-detect (block 0 publishes flag). [kept from round 12]
// ---------------------------------------------------------------------------
#define NT 18
struct CvtArgs {
  const void* src[NT];
  void*       dst[NT];
  int ccum[NT + 1];
  int nel[NT];
};

__global__ __launch_bounds__(256)
void cvt_kernel(CvtArgs a, const unsigned short* __restrict__ x0,
                int* __restrict__ flagp)
{
  __shared__ int sbad;
  if (threadIdx.x == 0) sbad = 0;
  __syncthreads();
  {
    float v = bf2f(x0[threadIdx.x]);
    if (!(fabsf(v) <= 1e6f)) sbad = 1;   // benign race, same value
  }
  __syncthreads();
  const int isf32 = sbad;
  if (blockIdx.x == 0 && threadIdx.x == 0) *flagp = isf32;

  int c = blockIdx.x;
  int ti = 0;
  while (c >= a.ccum[ti + 1]) ti++;
  int j = (c - a.ccum[ti]) * 2048 + threadIdx.x * 8;
  if (j >= a.nel[ti]) return;
  if (isf32) {
    const float* s = (const float*)a.src[ti];
    f32x4 v0 = *(const f32x4*)(s + j);
    f32x4 v1 = *(const f32x4*)(s + j + 4);
    u16x8 o;
    #pragma unroll
    for (int k = 0; k < 4; k++) { o[k] = f2bbits(v0[k]); o[k + 4] = f2bbits(v1[k]); }
    *(u16x8*)((u16*)a.dst[ti] + j) = o;
  } else {
    *(u16x8*)((u16*)a.dst[ti] + j) = *(const u16x8*)((const u16*)a.src[ti] + j);
  }
}

// ---------------------------------------------------------------------------
// GEMM 128x128, BK=64, XOR-swizzled LDS, 2D grid (n fastest).
// EPI 0: store bf16   EPI 2: store bf16(gelu(acc+bias))
// ---------------------------------------------------------------------------
template<int EPI>
__global__ __launch_bounds__(256, 2)
void gemm_bt(const bf16* __restrict__ A, const bf16* __restrict__ W,
             int M, int N, int K,
             bf16* __restrict__ outB,
             const bf16* __restrict__ bias)
{
  __shared__ __align__(16) bhalf sA[128 * 64];
  __shared__ __align__(16) bhalf sW[128 * 64];
  const int n0   = blockIdx.x * 128;
  const int m0   = blockIdx.y * 128;
  const int t    = threadIdx.x;
  const int w    = t >> 6;
  const int lane = t & 63;
  const int wm   = (w >> 1) * 64;
  const int wn   = (w & 1) * 64;
  const int lr   = lane & 15;
  const int lq   = lane >> 4;

  f32x4 acc[4][4];
  #pragma unroll
  for (int i = 0; i < 4; i++)
    #pragma unroll
    for (int j = 0; j < 4; j++)
      acc[i][j] = (f32x4){0.f, 0.f, 0.f, 0.f};

  for (int k0 = 0; k0 < K; k0 += 64) {
    #pragma unroll
    for (int j = 0; j < 4; j++) {
      int s  = t + 256 * j;
      int r  = s >> 3;
      int cs = (s & 7) ^ (r & 7);
      load_lds16(A + (size_t)(m0 + r) * K + k0 + cs * 8, sA + s * 8);
      int wr = n0 + r; wr = wr < N ? wr : N - 1;
      load_lds16(W + (size_t)wr * K + k0 + cs * 8, sW + s * 8);
    }
    __syncthreads();
    #pragma unroll
    for (int kk = 0; kk < 2; kk++) {
      bhalf8 af[4], bfr[4];
      #pragma unroll
      for (int i = 0; i < 4; i++) {
        int r = wm + i * 16 + lr;
        int c = (kk * 4 + lq) ^ (r & 7);
        af[i] = *(const bhalf8*)(sA + r * 64 + c * 8);
      }
      #pragma unroll
      for (int j = 0; j < 4; j++) {
        int r = wn + j * 16 + lr;
        int c = (kk * 4 + lq) ^ (r & 7);
        bfr[j] = *(const bhalf8*)(sW + r * 64 + c * 8);
      }
      #pragma unroll
      for (int i = 0; i < 4; i++)
        #pragma unroll
        for (int j = 0; j < 4; j++)
          acc[i][j] = __builtin_amdgcn_mfma_f32_16x16x32_bf16(af[i], bfr[j], acc[i][j], 0, 0, 0);
    }
    __syncthreads();
  }

  #pragma unroll
  for (int i = 0; i < 4; i++) {
    #pragma unroll
    for (int j = 0; j < 4; j++) {
      #pragma unroll
      for (int r = 0; r < 4; r++) {
        int m = m0 + wm + i * 16 + lq * 4 + r;
        int n = n0 + wn + j * 16 + lr;
        if (n < N) {
          float v = acc[i][j][r];
          size_t idx = (size_t)m * N + n;
          if (EPI == 0) {
            outB[idx] = __float2bfloat16(v);
          } else {
            v += __bfloat162float(bias[n]);
            outB[idx] = __float2bfloat16(0.5f * v * (1.0f + erff(v * 0.70710678118654752f)));
          }
        }
      }
    }
  }
}

// ---------------------------------------------------------------------------
// Skinny GEMM 64x128 tile, split-K=2 (N=1024): 1024 blocks (4/CU),
// fp32 partials; epilogues live in the reduce kernels. [SK=4 reverted]
// ---------------------------------------------------------------------------
__global__ __launch_bounds__(256, 4)
void gemm_skinny_sk(const bf16* __restrict__ A, const bf16* __restrict__ W,
                    int M, int N, int K,
                    float* __restrict__ p0, float* __restrict__ p1)
{
  __shared__ __align__(16) bhalf sA[64 * 64];
  __shared__ __align__(16) bhalf sW[128 * 64];
  const int id   = blockIdx.x;
  const int z    = id >> 9;
  const int id9  = id & 511;
  const int hi   = id9 >> 6;
  const int rem  = id9 & 63;
  const int jn   = rem >> 3;
  const int mi   = hi * 8 + (rem & 7);
  const int m0   = mi * 64;
  const int n0   = jn * 128;
  const int t    = threadIdx.x;
  const int w    = t >> 6;
  const int lane = t & 63;
  const int wm   = (w >> 1) * 32;
  const int wn   = (w & 1) * 64;
  const int lr   = lane & 15;
  const int lq   = lane >> 4;

  f32x4 acc[2][4];
  #pragma unroll
  for (int i = 0; i < 2; i++)
    #pragma unroll
    for (int j = 0; j < 4; j++)
      acc[i][j] = (f32x4){0.f, 0.f, 0.f, 0.f};

  const int kh = K >> 1;
  const int kend = z * kh + kh;
  for (int k0 = z * kh; k0 < kend; k0 += 64) {
    #pragma unroll
    for (int j = 0; j < 2; j++) {
      int s  = t + 256 * j;
      int r  = s >> 3;
      int cs = (s & 7) ^ (r & 7);
      load_lds16(A + (size_t)(m0 + r) * K + k0 + cs * 8, sA + s * 8);
    }
    #pragma unroll
    for (int j = 0; j < 4; j++) {
      int s  = t + 256 * j;
      int r  = s >> 3;
      int cs = (s & 7) ^ (r & 7);
      load_lds16(W + (size_t)(n0 + r) * K + k0 + cs * 8, sW + s * 8);
    }
    __syncthreads();
    #pragma unroll
    for (int kk = 0; kk < 2; kk++) {
      bhalf8 af[2], bfr[4];
      #pragma unroll
      for (int i = 0; i < 2; i++) {
        int r = wm + i * 16 + lr;
        int c = (kk * 4 + lq) ^ (r & 7);
        af[i] = *(const bhalf8*)(sA + r * 64 + c * 8);
      }
      #pragma unroll
      for (int j = 0; j < 4; j++) {
        int r = wn + j * 16 + lr;
        int c = (kk * 4 + lq) ^ (r & 7);
        bfr[j] = *(const bhalf8*)(sW + r * 64 + c * 8);
      }
      #pragma unroll
      for (int i = 0; i < 2; i++)
        #pragma unroll
        for (int j = 0; j < 4; j++)
          acc[i][j] = __builtin_amdgcn_mfma_f32_16x16x32_bf16(af[i], bfr[j], acc[i][j], 0, 0, 0);
    }
    __syncthreads();
  }

  float* out = z ? p1 : p0;
  #pragma unroll
  for (int i = 0; i < 2; i++)
    #pragma unroll
    for (int j = 0; j < 4; j++)
      #pragma unroll
      for (int r = 0; r < 4; r++) {
        int m = m0 + wm + i * 16 + lq * 4 + r;
        int n = n0 + wn + j * 16 + lr;
        out[(size_t)m * N + n] = acc[i][j][r];
      }
}

// ---------------------------------------------------------------------------
// out_proj reduce + residual + FULL ln2, one block per row.
// ---------------------------------------------------------------------------
__global__ __launch_bounds__(256)
void reduce_out_ln2_kernel(const float* __restrict__ p0, const float* __restrict__ p1,
                           const bf16* __restrict__ resB, float* __restrict__ x2f,
                           const bf16* __restrict__ w, const bf16* __restrict__ b,
                           bf16* __restrict__ hln)
{
  int row = blockIdx.x, t = threadIdx.x;
  int i = row * 256 + t;
  __shared__ float rs[4], rq[4];
  f32x4 a = ((const f32x4*)p0)[i];
  f32x4 bb = ((const f32x4*)p1)[i];
  u16x4 r = ((const u16x4*)resB)[i];
  f32x4 o;
  float s = 0.f, ss = 0.f;
  #pragma unroll
  for (int j = 0; j < 4; j++) {
    o[j] = a[j] + bb[j] + bf2f(r[j]);
    s += o[j]; ss += o[j] * o[j];
  }
  ((f32x4*)x2f)[i] = o;
  #pragma unroll
  for (int off = 32; off; off >>= 1) { s += __shfl_down(s, off); ss += __shfl_down(ss, off); }
  if ((t & 63) == 0) { rs[t >> 6] = s; rq[t >> 6] = ss; }
  __syncthreads();
  float S = rs[0] + rs[1] + rs[2] + rs[3];
  float Q = rq[0] + rq[1] + rq[2] + rq[3];
  float mean = S * (1.f / D_MODEL);
  float rstd = rsqrtf(Q * (1.f / D_MODEL) - mean * mean + 1e-5f);
  u16x4 wv = ((const u16x4*)w)[t];
  u16x4 bv = ((const u16x4*)b)[t];
  u16x4 ov;
  #pragma unroll
  for (int j = 0; j < 4; j++)
    ov[j] = f2bbits((o[j] - mean) * rstd * bf2f(wv[j]) + bf2f(bv[j]));
  ((u16x4*)hln)[i] = ov;
}

// ---------------------------------------------------------------------------
// ffn2 reduce: d_out = p0+p1 + bias + resF (dtype per flag)
// ---------------------------------------------------------------------------
__global__ __launch_bounds__(256)
void reduce_ffn_kernel(const float* __restrict__ p0, const float* __restrict__ p1,
                       const bf16* __restrict__ bias, const float* __restrict__ resF,
                       void* __restrict__ outp, const int* __restrict__ flagp)
{
  int i = blockIdx.x * 256 + threadIdx.x;
  int n4 = i & (D_MODEL / 4 - 1);
  f32x4 v0 = ((const f32x4*)p0)[i];
  f32x4 v1 = ((const f32x4*)p1)[i];
  f32x4 rf = ((const f32x4*)resF)[i];
  u16x4 bb = ((const u16x4*)bias)[n4];
  f32x4 o;
  #pragma unroll
  for (int j = 0; j < 4; j++)
    o[j] = v0[j] + v1[j] + rf[j] + bf2f(bb[j]);
  if (*flagp) {
    ((f32x4*)outp)[i] = o;
  } else {
    u16x4 ov;
    #pragma unroll
    for (int j = 0; j < 4; j++) ov[j] = f2bbits(o[j]);
    ((u16x4*)outp)[i] = ov;
  }
}

// ---------------------------------------------------------------------------
// Fused ln0 + ln1; reads x directly from d_in (fp32/bf16 per flag); float4.
// ---------------------------------------------------------------------------
__global__ __launch_bounds__(256)
void ln01_kernel(const void* __restrict__ xin, const int* __restrict__ flagp,
                 const bf16* __restrict__ w0, const bf16* __restrict__ b0,
                 const bf16* __restrict__ w1, const bf16* __restrict__ b1,
                 bf16* __restrict__ x0o, bf16* __restrict__ x1o)
{
  int row = blockIdx.x, t = threadIdx.x;
  int i = row * 256 + t;
  __shared__ float rs[4], rq[4];
  float v[4], s = 0.f, ss = 0.f;
  if (*flagp) {
    f32x4 xv = ((const f32x4*)xin)[i];
    #pragma unroll
    for (int j = 0; j < 4; j++) v[j] = xv[j];
  } else {
    u16x4 xv = ((const u16x4*)xin)[i];
    #pragma unroll
    for (int j = 0; j < 4; j++) v[j] = bf2f(xv[j]);
  }
  #pragma unroll
  for (int j = 0; j < 4; j++) { s += v[j]; ss += v[j] * v[j]; }
  #pragma unroll
  for (int o = 32; o; o >>= 1) { s += __shfl_down(s, o); ss += __shfl_down(ss, o); }
  if ((t & 63) == 0) { rs[t >> 6] = s; rq[t >> 6] = ss; }
  __syncthreads();
  float S = rs[0] + rs[1] + rs[2] + rs[3];
  float Q = rq[0] + rq[1] + rq[2] + rq[3];
  float mean = S * (1.f / D_MODEL);
  float rstd = rsqrtf(Q * (1.f / D_MODEL) - mean * mean + 1e-5f);
  u16x4 w0v = ((const u16x4*)w0)[t], b0v = ((const u16x4*)b0)[t];
  float u[4]; s = 0.f; ss = 0.f;
  u16x4 o0;
  #pragma unroll
  for (int j = 0; j < 4; j++) {
    u[j] = (v[j] - mean) * rstd * bf2f(w0v[j]) + bf2f(b0v[j]);
    s += u[j]; ss += u[j] * u[j];
    o0[j] = f2bbits(u[j]);
  }
  ((u16x4*)x0o)[i] = o0;
  __syncthreads();
  #pragma unroll
  for (int o = 32; o; o >>= 1) { s += __shfl_down(s, o); ss += __shfl_down(ss, o); }
  if ((t & 63) == 0) { rs[t >> 6] = s; rq[t >> 6] = ss; }
  __syncthreads();
  S = rs[0] + rs[1] + rs[2] + rs[3];
  Q = rq[0] + rq[1] + rq[2] + rq[3];
  mean = S * (1.f / D_MODEL);
  rstd = rsqrtf(Q * (1.f / D_MODEL) - mean * mean + 1e-5f);
  u16x4 w1v = ((const u16x4*)w1)[t], b1v = ((const u16x4*)b1)[t];
  u16x4 o1;
  #pragma unroll
  for (int j = 0; j < 4; j++)
    o1[j] = f2bbits((u[j] - mean) * rstd * bf2f(w1v[j]) + bf2f(b1v[j]));
  ((u16x4*)x1o)[i] = o1;
}

// ---------------------------------------------------------------------------
// Causal depthwise conv (k=4) + SiLU -> bf16 xact, vectorized 8 ch/thread.
// ---------------------------------------------------------------------------
__device__ __forceinline__ void conv8(const bf16* __restrict__ zxb,
                                      const bf16* __restrict__ cw,
                                      const bf16* __restrict__ cb,
                                      bf16* __restrict__ xact, int row, int c0)
{
  int l = row & (SEQ - 1);
  float acc[8];
  {
    bhalf8 cbv = *(const bhalf8*)(cb + c0);
    #pragma unroll
    for (int j = 0; j < 8; j++) acc[j] = (float)cbv[j];
  }
  bhalf wts[32];
  #pragma unroll
  for (int q = 0; q < 4; q++)
    *(bhalf8*)(wts + q * 8) = *(const bhalf8*)(cw + c0 * 4 + q * 8);
  #pragma unroll
  for (int k = 0; k < 4; k++) {
    int lt = l - 3 + k;
    if (lt >= 0) {
      bhalf8 xv = *(const bhalf8*)(zxb + (size_t)(row - 3 + k) * D_IN_PROJ + D_INNER + c0);
      #pragma unroll
      for (int j = 0; j < 8; j++)
        acc[j] = fmaf((float)xv[j], (float)wts[j * 4 + k], acc[j]);
    }
  }
  bhalf8 o;
  #pragma unroll
  for (int j = 0; j < 8; j++) {
    float a = acc[j];
    o[j] = (bhalf)(a / (1.f + expf(-a)));
  }
  *(bhalf8*)(xact + (size_t)row * CONV_DIM + c0) = o;
}

__global__ __launch_bounds__(256)
void conv_silu_dt_kernel(const bf16* __restrict__ zxb, const bf16* __restrict__ cw,
                         const bf16* __restrict__ cb, bf16* __restrict__ xact,
                         const bf16* __restrict__ dtb, const bf16* __restrict__ alog,
                         float* __restrict__ dts, float* __restrict__ ldab)
{
  const int row = blockIdx.y;
  const int t = threadIdx.x;
  if (blockIdx.x == 0) {
    conv8(zxb, cw, cb, xact, row, t * 8);
  } else {
    if (t < 16) {
      conv8(zxb, cw, cb, xact, row, 2048 + t * 8);
    } else if (t < 48) {
      int h = t - 16;
      float v = __bfloat162float(zxb[(size_t)row * D_IN_PROJ + (D_INNER + CONV_DIM) + h]) +
                __bfloat162float(dtb[h]);
      float sp = (v > 20.f) ? v : log1pf(expf(v));
      dts[row * NHEADS + h] = sp;
      ldab[row * NHEADS + h] = -sp * expf(__bfloat162float(alog[h]));
    }
  }
}

// ---------------------------------------------------------------------------
// MFMA chunk scan, pass 1 (chunk states).
// ---------------------------------------------------------------------------
__global__ __launch_bounds__(256)
void scan_state_kernel(const bf16* __restrict__ xact, const float* __restrict__ dts,
                       const float* __restrict__ ldab, bf16* __restrict__ Sbuf,
                       float* __restrict__ acb)
{
  __shared__ __align__(16) bf16 wBT[64][72];
  __shared__ __align__(16) bf16 XT[64][72];
  __shared__ float lsS[64], dtS[64];
  const int bid = blockIdx.x;
  const int bh = bid & 63, c = bid >> 6;
  const int b = bh >> 5, h = bh & 31;
  const int t0 = c * TC;
  const int tid = threadIdx.x;
  const int w = tid >> 6, lane = tid & 63;
  const int lr = lane & 15, lq = lane >> 4;

  if (w == 0) {
    float v = ldab[(size_t)(b * SEQ + t0 + lane) * NHEADS + h];
    #pragma unroll
    for (int o = 1; o < 64; o <<= 1) {
      float up = __shfl_up(v, o);
      if (lane >= o) v += up;
    }
    lsS[lane] = v;
    dtS[lane] = dts[(size_t)(b * SEQ + t0 + lane) * NHEADS + h];
  }
  __syncthreads();
  const float lsT = lsS[63];
  {
    int nn = tid & 63, u0 = (tid >> 6) * 16;
    for (int i = 0; i < 16; i++) {
      int u = u0 + i;
      const bf16* rowp = xact + (size_t)(b * SEQ + t0 + u) * CONV_DIM;
      float wgt = dtS[u] * __expf(lsT - lsS[u]);
      wBT[nn][u] = __float2bfloat16(__bfloat162float(rowp[D_INNER + nn]) * wgt);
      XT[nn][u]  = rowp[h * 64 + nn];
    }
  }
  __syncthreads();

  bhalf8 af0 = *(const bhalf8*)&wBT[16 * w + lr][lq * 8];
  bhalf8 af1 = *(const bhalf8*)&wBT[16 * w + lr][32 + lq * 8];
  bf16* sb = Sbuf + ((size_t)bh * NCH + c) * 4096;
  #pragma unroll
  for (int jt = 0; jt < 4; jt++) {
    bhalf8 xf0 = *(const bhalf8*)&XT[16 * jt + lr][lq * 8];
    bhalf8 xf1 = *(const bhalf8*)&XT[16 * jt + lr][32 + lq * 8];
    f32x4 acc = (f32x4){0.f, 0.f, 0.f, 0.f};
    acc = __builtin_amdgcn_mfma_f32_16x16x32_bf16(af0, xf0, acc, 0, 0, 0);
    acc = __builtin_amdgcn_mfma_f32_16x16x32_bf16(af1, xf1, acc, 0, 0, 0);
    #pragma unroll
    for (int r = 0; r < 4; r++) {
      int n = 16 * w + lq * 4 + r;
      int p = 16 * jt + lr;
      sb[p * 64 + n] = __float2bfloat16(acc[r]);
    }
  }
  if (tid == 0) acb[bh * NCH + c] = __expf(lsT);
}

// ---------------------------------------------------------------------------
// Pass 2: serial inter-chunk propagation (in-place).
// ---------------------------------------------------------------------------
__global__ __launch_bounds__(256)
void state_prop_kernel(bf16* __restrict__ Sbuf, const float* __restrict__ acb)
{
  const int bh = blockIdx.x >> 2, q = blockIdx.x & 3;
  const int t = threadIdx.x;
  bf16* sp = Sbuf + (size_t)bh * NCH * 4096 + q * 1024 + t;
  const float* ap = acb + bh * NCH;
  float h0 = 0.f, h1 = 0.f, h2 = 0.f, h3 = 0.f;
  for (int c = 0; c < NCH; c++) {
    bf16* pc = sp + (size_t)c * 4096;
    float s0 = __bfloat162float(pc[0]);
    float s1 = __bfloat162float(pc[256]);
    float s2 = __bfloat162float(pc[512]);
    float s3 = __bfloat162float(pc[768]);
    float a = ap[c];
    pc[0]   = __float2bfloat16(h0);
    pc[256] = __float2bfloat16(h1);
    pc[512] = __float2bfloat16(h2);
    pc[768] = __float2bfloat16(h3);
    h0 = fmaf(h0, a, s0); h1 = fmaf(h1, a, s1);
    h2 = fmaf(h2, a, s2); h3 = fmaf(h3, a, s3);
  }
}

// ---------------------------------------------------------------------------
// MFMA chunk scan, pass 3. 4-tile LDS (M round-trips through Bs). [round 12]
// ---------------------------------------------------------------------------
__global__ __launch_bounds__(256)
void scan_y_kernel(const bf16* __restrict__ xact, const float* __restrict__ dts,
                   const float* __restrict__ ldab, const bf16* __restrict__ Sbuf,
                   bf16* __restrict__ yfull)
{
  __shared__ __align__(16) bf16 Cs[64][72];
  __shared__ __align__(16) bf16 Bs[64][72];    // reused for M after G loop
  __shared__ __align__(16) bf16 XT[64][72];
  __shared__ __align__(16) bf16 HT[64][72];
  __shared__ float lsS[64], dtS[64];
  const int bid = blockIdx.x;
  const int bh = bid & 63, c = bid >> 6;
  const int b = bh >> 5, h = bh & 31;
  const int t0 = c * TC;
  const int tid = threadIdx.x;
  const int w = tid >> 6, lane = tid & 63;
  const int lr = lane & 15, lq = lane >> 4;

  if (w == 0) {
    float v = ldab[(size_t)(b * SEQ + t0 + lane) * NHEADS + h];
    #pragma unroll
    for (int o = 1; o < 64; o <<= 1) {
      float up = __shfl_up(v, o);
      if (lane >= o) v += up;
    }
    lsS[lane] = v;
    dtS[lane] = dts[(size_t)(b * SEQ + t0 + lane) * NHEADS + h];
  }
  {
    int nn = tid & 63, u0 = (tid >> 6) * 16;
    for (int i = 0; i < 16; i++) {
      int u = u0 + i;
      const bf16* rowp = xact + (size_t)(b * SEQ + t0 + u) * CONV_DIM;
      Bs[u][nn] = rowp[D_INNER + nn];
      Cs[u][nn] = rowp[D_INNER + 64 + nn];
      XT[nn][u] = rowp[h * 64 + nn];
    }
    const bf16* sb = Sbuf + ((size_t)bh * NCH + c) * 4096;
    for (int i = 0; i < 16; i++) {
      int e = tid + 256 * i;
      HT[e >> 6][e & 63] = sb[e];
    }
  }
  __syncthreads();

  bhalf8 cf0 = *(const bhalf8*)&Cs[16 * w + lr][lq * 8];
  bhalf8 cf1 = *(const bhalf8*)&Cs[16 * w + lr][32 + lq * 8];
  f32x4 accH[4];
  float mreg[4][4];
  #pragma unroll
  for (int jt = 0; jt < 4; jt++) {
    bhalf8 bf0 = *(const bhalf8*)&Bs[16 * jt + lr][lq * 8];
    bhalf8 bf1 = *(const bhalf8*)&Bs[16 * jt + lr][32 + lq * 8];
    f32x4 g = (f32x4){0.f, 0.f, 0.f, 0.f};
    g = __builtin_amdgcn_mfma_f32_16x16x32_bf16(cf0, bf0, g, 0, 0, 0);
    g = __builtin_amdgcn_mfma_f32_16x16x32_bf16(cf1, bf1, g, 0, 0, 0);
    bhalf8 hf0 = *(const bhalf8*)&HT[16 * jt + lr][lq * 8];
    bhalf8 hf1 = *(const bhalf8*)&HT[16 * jt + lr][32 + lq * 8];
    f32x4 ah = (f32x4){0.f, 0.f, 0.f, 0.f};
    ah = __builtin_amdgcn_mfma_f32_16x16x32_bf16(cf0, hf0, ah, 0, 0, 0);
    ah = __builtin_amdgcn_mfma_f32_16x16x32_bf16(cf1, hf1, ah, 0, 0, 0);
    accH[jt] = ah;
    #pragma unroll
    for (int r = 0; r < 4; r++) {
      int t = 16 * w + lq * 4 + r;
      int u = 16 * jt + lr;
      float m = 0.f;
      if (u <= t) m = g[r] * __expf(lsS[t] - lsS[u]) * dtS[u];
      mreg[jt][r] = m;
    }
  }
  __syncthreads();               // all Bs reads complete
  #pragma unroll
  for (int jt = 0; jt < 4; jt++)
    #pragma unroll
    for (int r = 0; r < 4; r++)
      Bs[16 * w + lq * 4 + r][16 * jt + lr] = __float2bfloat16(mreg[jt][r]);
  __syncthreads();

  bhalf8 mf0 = *(const bhalf8*)&Bs[16 * w + lr][lq * 8];
  bhalf8 mf1 = *(const bhalf8*)&Bs[16 * w + lr][32 + lq * 8];
  #pragma unroll
  for (int jt = 0; jt < 4; jt++) {
    bhalf8 xf0 = *(const bhalf8*)&XT[16 * jt + lr][lq * 8];
    bhalf8 xf1 = *(const bhalf8*)&XT[16 * jt + lr][32 + lq * 8];
    f32x4 acc = (f32x4){0.f, 0.f, 0.f, 0.f};
    acc = __builtin_amdgcn_mfma_f32_16x16x32_bf16(mf0, xf0, acc, 0, 0, 0);
    acc = __builtin_amdgcn_mfma_f32_16x16x32_bf16(mf1, xf1, acc, 0, 0, 0);
    #pragma unroll
    for (int r = 0; r < 4; r++) {
      int t = 16 * w + lq * 4 + r;
      int p = 16 * jt + lr;
      float y = acc[r] + __expf(lsS[t]) * accH[jt][r];
      yfull[(size_t)(b * SEQ + t0 + t) * D_INNER + h * 64 + p] = __float2bfloat16(y);
    }
  }
}

// ---------------------------------------------------------------------------
// y = yfull + D*x;  y *= silu(z);  RMSNorm * norm_w -> bf16.
// ---------------------------------------------------------------------------
__global__ __launch_bounds__(256)
void gate_rms_kernel(const bf16* __restrict__ yfull, const bf16* __restrict__ xact,
                     const bf16* __restrict__ zxb, const bf16* __restrict__ Dp,
                     const bf16* __restrict__ nw, bf16* __restrict__ yn)
{
  int row = blockIdx.x, t = threadIdx.x;
  int c0 = t * 8;
  __shared__ float rq[4];
  bhalf8 yv8 = *(const bhalf8*)(yfull + (size_t)row * D_INNER + c0);
  bhalf8 xv8 = *(const bhalf8*)(xact + (size_t)row * CONV_DIM + c0);
  bhalf8 zv8 = *(const bhalf8*)(zxb + (size_t)row * D_IN_PROJ + c0);
  float Dv = __bfloat162float(Dp[c0 >> 6]);
  float yv[8]; float ss = 0.f;
  #pragma unroll
  for (int j = 0; j < 8; j++) {
    float y = (float)yv8[j] + Dv * (float)xv8[j];
    float z = (float)zv8[j];
    yv[j] = y * (z / (1.f + expf(-z)));
    ss += yv[j] * yv[j];
  }
  #pragma unroll
  for (int o = 32; o; o >>= 1) ss += __shfl_down(ss, o);
  if ((t & 63) == 0) rq[t >> 6] = ss;
  __syncthreads();
  float tot = rq[0] + rq[1] + rq[2] + rq[3];
  float rr = rsqrtf(tot * (1.f / D_INNER) + 1e-5f);
  bhalf8 nv8 = *(const bhalf8*)(nw + c0);
  bhalf8 o;
  #pragma unroll
  for (int j = 0; j < 8; j++)
    o[j] = (bhalf)(yv[j] * rr * (float)nv8[j]);
  *(bhalf8*)(yn + (size_t)row * D_INNER + c0) = o;
}

// ---------------------------------------------------------------------------
extern "C" void kernel_launch(void* const* d_in, const int* in_sizes, int n_in,
                              void* d_out, int out_size, void* d_ws, size_t ws_size,
                              hipStream_t stream)
{
  char* ws = (char*)d_ws;
  bf16*  x1b   = (bf16*) (ws + 0);           //  [3->4]
  bf16*  Sbuf  = (bf16*) (ws + 0);           //  [7->9]   alias x1b (dead @4)
  bf16*  ynb   = (bf16*) (ws + 0);           //  [10->11] alias Sbuf
  float* pf0   = (float*)(ws + 0);           //  [14->14b] alias ynb
  bf16*  wproj = (bf16*) (ws + 16777216);    //  [2->4]
  float* acb   = (float*)(ws + 16777216);    //  [7->8]   alias wproj
  float* dtsb  = (float*)(ws + 16785408);    //  [5->9]   alias wproj
  float* ldab  = (float*)(ws + 17309696);    //  [5->9]   alias wproj
  float* pf1   = (float*)(ws + 16777216);    //  [14->14b] alias wproj region
  bf16*  wout  = (bf16*) (ws + 25493504);    //  [2->11]
  bf16*  w1c   = (bf16*) (ws + 29687808);    //  [2->13]
  bf16*  w2c   = (bf16*) (ws + 38076416);    //  [2->14]
  bf16*  ln0w  = (bf16*) (ws + 46465024);
  bf16*  ln0b  = (bf16*) (ws + 46467072);
  bf16*  ln1w  = (bf16*) (ws + 46469120);
  bf16*  ln1b  = (bf16*) (ws + 46471168);
  bf16*  ln2w  = (bf16*) (ws + 46473216);
  bf16*  ln2b  = (bf16*) (ws + 46475264);
  bf16*  convw = (bf16*) (ws + 46477312);
  bf16*  convb = (bf16*) (ws + 46494720);
  bf16*  dtb   = (bf16*) (ws + 46499072);
  bf16*  alog  = (bf16*) (ws + 46499136);
  bf16*  Dp    = (bf16*) (ws + 46499200);
  bf16*  normw = (bf16*) (ws + 46499264);
  bf16*  b1c   = (bf16*) (ws + 46503360);
  bf16*  b2c   = (bf16*) (ws + 46511552);
  int*   flag  = (int*)  (ws + 46513600);
  bf16*  x0b   = (bf16*) (ws + 46514176);    //  [3->11b]
  bf16*  zxb   = (bf16*) (ws + 54902784);    //  [4->10]
  float* x2f   = (float*)(ws + 54902784);    //  [11b->14b] alias zxb
  bf16*  xact  = (bf16*) (ws + 89767936);    //  [5->10]
  float* pout0 = (float*)(ws + 89767936);    //  [11->11b] alias xact
  float* pout1 = (float*)(ws + 106545152);   //  [11->11b]
  bf16*  gbuf  = (bf16*) (ws + 89767936);    //  [13->14] alias xact region
  bf16*  yfull = (bf16*) (ws + 125419520);   //  [9->10]
  bf16*  hln   = (bf16*) (ws + 125419520);   //  [11b->13] alias yfull

  CvtArgs ca;
  void* dsts[NT] = { ln0w, ln0b, ln1w, ln1b, ln2w, ln2b, wproj, convw, convb,
                     dtb, alog, Dp, normw, wout, w1c, b1c, w2c, b2c };
  int cc = 0;
  ca.ccum[0] = 0;
  for (int i = 0; i < NT; i++) {
    ca.src[i] = d_in[i + 1];
    ca.dst[i] = dsts[i];
    ca.nel[i] = in_sizes[i + 1];
    cc += (in_sizes[i + 1] + 2047) / 2048;
    ca.ccum[i + 1] = cc;
  }
  cvt_kernel<<<cc, 256, 0, stream>>>(ca, (const unsigned short*)d_in[0], flag);

  ln01_kernel<<<NROWS, 256, 0, stream>>>(d_in[0], flag, ln0w, ln0b, ln1w, ln1b,
                                         x0b, x1b);

  gemm_bt<0><<<dim3(34, 32), 256, 0, stream>>>(x1b, wproj, NROWS, D_IN_PROJ, D_MODEL,
                                               zxb, nullptr);

  conv_silu_dt_kernel<<<dim3(2, NROWS), 256, 0, stream>>>(zxb, convw, convb, xact,
                                                          dtb, alog, dtsb, ldab);

  scan_state_kernel<<<NCH * 64, 256, 0, stream>>>(xact, dtsb, ldab, Sbuf, acb);
  state_prop_kernel<<<64 * 4, 256, 0, stream>>>(Sbuf, acb);
  scan_y_kernel<<<NCH * 64, 256, 0, stream>>>(xact, dtsb, ldab, Sbuf, yfull);

  gate_rms_kernel<<<NROWS, 256, 0, stream>>>(yfull, xact, zxb, Dp, normw, ynb);

  // out_proj: 64x128 split-K=2 -> partials, then fused reduce+residual+ln2
  gemm_skinny_sk<<<1024, 256, 0, stream>>>(ynb, wout, NROWS, D_MODEL, D_INNER,
                                           pout0, pout1);
  reduce_out_ln2_kernel<<<NROWS, 256, 0, stream>>>(pout0, pout1, x0b, x2f,
                                                   ln2w, ln2b, hln);

  gemm_bt<2><<<dim3(32, 32), 256, 0, stream>>>(hln, w1c, NROWS, FFN_DIM, D_MODEL,
                                               gbuf, b1c);

  // ffn2: 64x128 split-K=2 -> partials, then fused reduce(+bias+residual)
  gemm_skinny_sk<<<1024, 256, 0, stream>>>(gbuf, w2c, NROWS, D_MODEL, FFN_DIM,
                                           pf0, pf1);
  reduce_ffn_kernel<<<(NROWS * D_MODEL) / 1024, 256, 0, stream>>>(pf0, pf1,
                                                                  b2c, x2f, d_out, flag);
}